// Round 4
// baseline (776.766 us; speedup 1.0000x reference)
//
#include <hip/hip_runtime.h>
#include <hip/hip_bf16.h>

// Fused: out = swish(swish(groupnorm(x@W + b)) * mw)
// M=65536, K=1024, N=1024, G=32 (group width 32 channels)
//
// Kernel 0: x fp32 -> xb bf16 (row-major, RNE), pure streaming pass.
// Kernel 1: W fp32 [K][N] -> Wt bf16 [N][K] with per-row 16B-chunk XOR swizzle
//           (chunk c -> c ^ ((n>>1)&3)) so B-fragment ds_read_b128 from a
//           LINEAR global_load_lds destination is bank-uniform.
// Kernel 2: m97-structure 128x128x32 bf16 GEMM:
//           - BOTH operands staged bf16 via global_load_lds (async, no
//             reg round-trip, no in-loop VALU conversion).
//           - double-buffered LDS (32 KB total), ONE __syncthreads/K-step.
//           - XCD-bijective block remap (panel sharers adjacent on one L2).
//           - Epilogue: bias + GroupNorm + swish*mw*swish in-register.
// Fallback (ws too small for xb): Round-2 kernel (fp32 A, in-loop cvt).

typedef __attribute__((ext_vector_type(8))) short short8;
typedef __attribute__((ext_vector_type(4))) float floatx4;

#define K_DIM 1024
#define N_DIM 1024
#define BM 128
#define BN 128
#define BK 32
#define SA 40   // fallback kernel's padded As stride

__device__ __forceinline__ unsigned short f2bf(float f) {
    unsigned int u = __float_as_uint(f);
    u += 0x7FFFu + ((u >> 16) & 1u);
    return (unsigned short)(u >> 16);
}

// packed fp32x8 -> bf16x8 (RNE) via v_cvt_pk_bf16_f32
__device__ __forceinline__ short8 cvt8(floatx4 a, floatx4 b) {
    union { __hip_bfloat162 h[4]; short8 s; } u;
    u.h[0] = __float22bfloat162_rn(float2{a[0], a[1]});
    u.h[1] = __float22bfloat162_rn(float2{a[2], a[3]});
    u.h[2] = __float22bfloat162_rn(float2{b[0], b[1]});
    u.h[3] = __float22bfloat162_rn(float2{b[2], b[3]});
    return u.s;
}

// ---- Kernel 0: x fp32 -> bf16, streaming (8 elems/thread/iter) ----
__global__ __launch_bounds__(256) void prep_x_kernel(const float* __restrict__ x,
                                                     unsigned short* __restrict__ xb,
                                                     const long long nelem) {
    long long idx = (long long)(blockIdx.x * 256 + threadIdx.x) * 8;
    const long long stride = (long long)gridDim.x * 256 * 8;
    for (; idx < nelem; idx += stride) {
        floatx4 a = *(const floatx4*)(x + idx);
        floatx4 c = *(const floatx4*)(x + idx + 4);
        *(short8*)(xb + idx) = cvt8(a, c);
    }
}

// ---- Kernel 1: transpose + convert + chunk-swizzle W -> Wt (bf16, [N][K]) ----
__global__ __launch_bounds__(256) void prep_w_kernel(const float* __restrict__ W,
                                                     unsigned short* __restrict__ Wt) {
    __shared__ float s[32][33];
    const int tx = threadIdx.x & 31;
    const int ty = threadIdx.x >> 5;
    const int kt = (blockIdx.x & 31) << 5;
    const int nt = (blockIdx.x >> 5) << 5;
    #pragma unroll
    for (int i = 0; i < 4; ++i)
        s[ty + i * 8][tx] = W[(size_t)(kt + ty + i * 8) * N_DIM + nt + tx];
    __syncthreads();
    #pragma unroll
    for (int i = 0; i < 4; ++i) {
        const int n = nt + ty + i * 8;
        const int sw = (n >> 1) & 3;
        const int col = (((tx >> 3) ^ sw) << 3) | (tx & 7);
        Wt[(size_t)n * K_DIM + kt + col] = f2bf(s[tx][ty + i * 8]);
    }
}

// ---- shared epilogue: bias + GroupNorm(32) + swish * mw + swish ----
// C/D layout: col = ln, row = q*4 + r. Wave covers cols n0 + wn*64 + in*16 + ln.
__device__ __forceinline__ void epilogue(floatx4 (&acc)[4][4], int m0, int n0,
                                         int wm, int wn, int q, int ln,
                                         const float* __restrict__ bias,
                                         const float* __restrict__ mulw,
                                         float* __restrict__ out) {
    float bv[4], wv[4];
    #pragma unroll
    for (int in = 0; in < 4; ++in) {
        int col = n0 + wn * 64 + in * 16 + ln;
        bv[in] = bias[col];
        wv[in] = mulw[col];
    }
    #pragma unroll
    for (int im = 0; im < 4; ++im)
        #pragma unroll
        for (int in = 0; in < 4; ++in)
            #pragma unroll
            for (int r = 0; r < 4; ++r)
                acc[im][in][r] += bv[in];

    const float inv32 = 1.0f / 32.0f;
    #pragma unroll
    for (int im = 0; im < 4; ++im) {
        const int rowb = m0 + wm * 64 + im * 16 + q * 4;
        #pragma unroll
        for (int p = 0; p < 2; ++p) {   // group p covers tiles in=2p, 2p+1
            const int i0 = 2 * p, i1 = 2 * p + 1;
            float mean[4], rstd[4];
            #pragma unroll
            for (int r = 0; r < 4; ++r) {
                float y0 = acc[im][i0][r], y1 = acc[im][i1][r];
                float s1 = y0 + y1;
                float s2 = y0 * y0 + y1 * y1;
                #pragma unroll
                for (int d = 1; d < 16; d <<= 1) {
                    s1 += __shfl_xor(s1, d, 64);
                    s2 += __shfl_xor(s2, d, 64);
                }
                float mn = s1 * inv32;
                float var = s2 * inv32 - mn * mn;
                mean[r] = mn;
                rstd[r] = rsqrtf(var + 1e-5f);
            }
            #pragma unroll
            for (int ii = i0; ii <= i1; ++ii) {
                const int col = n0 + wn * 64 + ii * 16 + ln;
                const float w = wv[ii];
                #pragma unroll
                for (int r = 0; r < 4; ++r) {
                    float y   = acc[im][ii][r];
                    float nrm = (y - mean[r]) * rstd[r];
                    float s   = nrm / (1.0f + __expf(-nrm));
                    float m2  = s * w;
                    float o   = m2 / (1.0f + __expf(-m2));
                    out[(size_t)(rowb + r) * N_DIM + col] = o;
                }
            }
        }
    }
}

// ---- Kernel 2: fused GEMM (both operands bf16 via global_load_lds) ----
__global__ __launch_bounds__(256) void fused_kernel(const unsigned short* __restrict__ xb,
                                                    const unsigned short* __restrict__ Wt,
                                                    const float* __restrict__ bias,
                                                    const float* __restrict__ mulw,
                                                    float* __restrict__ out) {
    __shared__ unsigned short As[2 * BM * BK];   // 2 x 8 KB, linear
    __shared__ unsigned short Bs[2 * BN * BK];   // 2 x 8 KB, linear

    const int tid  = threadIdx.x;
    const int lane = tid & 63;
    const int wid  = tid >> 6;
    const int wm   = wid >> 1;
    const int wn   = wid & 1;
    const int q    = lane >> 4;
    const int ln   = lane & 15;

    // XCD-bijective remap: 8 blocks sharing an x row-panel adjacent on ONE XCD.
    const int bid  = blockIdx.x;
    const int xcd  = bid & 7;
    const int lid  = bid >> 3;
    const int bRow = xcd * 64 + (lid >> 3);
    const int bCol = lid & 7;
    const int m0 = bRow * BM;
    const int n0 = bCol * BN;

    floatx4 acc[4][4];
    #pragma unroll
    for (int i = 0; i < 4; ++i)
        #pragma unroll
        for (int j = 0; j < 4; ++j)
            acc[i][j] = (floatx4){0.f, 0.f, 0.f, 0.f};

    // staging sources: wave wid, issue j covers 16 rows; 4 lanes per row (16B each)
    const unsigned short* xap = xb + (size_t)(m0 + wid * 32 + (lane >> 2)) * K_DIM + ((lane & 3) << 3);
    const unsigned short* wtp = Wt + (size_t)(n0 + wid * 32 + (lane >> 2)) * K_DIM + ((lane & 3) << 3);

    // fragment read bases (lin [128][32]; A uniform-by-construction, B pre-swizzled)
    const unsigned short* ard = As + (wm * 64 + ln) * BK + (q << 3);
    const int swb = (ln >> 1) & 3;
    const unsigned short* brd = Bs + (wn * 64 + ln) * BK + ((q ^ swb) << 3);

#define STAGE(buf, koff)                                                                   \
    do {                                                                                   \
        _Pragma("unroll")                                                                  \
        for (int j = 0; j < 2; ++j) {                                                      \
            __builtin_amdgcn_global_load_lds(                                              \
                (const __attribute__((address_space(1))) unsigned int*)(xap + (size_t)j * 16 * K_DIM + (koff)), \
                (__attribute__((address_space(3))) unsigned int*)(As + (buf) * (BM * BK) + (wid * 2 + j) * 512), \
                16, 0, 0);                                                                 \
            __builtin_amdgcn_global_load_lds(                                              \
                (const __attribute__((address_space(1))) unsigned int*)(wtp + (size_t)j * 16 * K_DIM + (koff)), \
                (__attribute__((address_space(3))) unsigned int*)(Bs + (buf) * (BN * BK) + (wid * 2 + j) * 512), \
                16, 0, 0);                                                                 \
        }                                                                                  \
    } while (0)

    STAGE(0, 0);
    __syncthreads();

    int cur = 0;
    for (int k0 = 0; k0 < K_DIM; k0 += BK) {
        const int knext = (k0 + BK) & (K_DIM - 1);   // wrap: last prefetch benign
        const int nxt = cur ^ 1;

        STAGE(nxt, knext);   // async, in flight across this iteration's MFMA

        short8 af[4], bfv[4];
        #pragma unroll
        for (int im = 0; im < 4; ++im)
            af[im] = *(const short8*)(ard + cur * (BM * BK) + im * 16 * BK);
        #pragma unroll
        for (int in = 0; in < 4; ++in)
            bfv[in] = *(const short8*)(brd + cur * (BN * BK) + in * 16 * BK);
        #pragma unroll
        for (int im = 0; im < 4; ++im)
            #pragma unroll
            for (int in = 0; in < 4; ++in)
                acc[im][in] = __builtin_amdgcn_mfma_f32_16x16x32_bf16(
                    af[im], bfv[in], acc[im][in], 0, 0, 0);

        __syncthreads();   // drains vmcnt: nxt buffers complete; cur safe to overwrite
        cur = nxt;
    }
#undef STAGE

    epilogue(acc, m0, n0, wm, wn, q, ln, bias, mulw, out);
}

// ---- Fallback (ws too small for xb): Round-2 kernel, fp32 A with in-loop cvt ----
__global__ __launch_bounds__(256) void fused_kernel_fb(const float* __restrict__ x,
                                                       const unsigned short* __restrict__ Wt,
                                                       const float* __restrict__ bias,
                                                       const float* __restrict__ mulw,
                                                       float* __restrict__ out) {
    __shared__ unsigned short As[2 * BM * SA];
    __shared__ unsigned short Bs[2 * BN * BK];

    const int tid  = threadIdx.x;
    const int lane = tid & 63;
    const int wid  = tid >> 6;
    const int wm   = wid >> 1;
    const int wn   = wid & 1;
    const int q    = lane >> 4;
    const int ln   = lane & 15;

    const int bid  = blockIdx.x;
    const int xcd  = bid & 7;
    const int lid  = bid >> 3;
    const int bRow = xcd * 64 + (lid >> 3);
    const int bCol = lid & 7;
    const int m0 = bRow * BM;
    const int n0 = bCol * BN;

    floatx4 acc[4][4];
    #pragma unroll
    for (int i = 0; i < 4; ++i)
        #pragma unroll
        for (int j = 0; j < 4; ++j)
            acc[i][j] = (floatx4){0.f, 0.f, 0.f, 0.f};

    const int arow = tid >> 1;
    const int acol = (tid & 1) << 4;
    const float* xptr = x + (size_t)(m0 + arow) * K_DIM + acol;
    unsigned short* aw = As + arow * SA + acol;

    const unsigned short* wtp = Wt + (size_t)(n0 + wid * 32 + (lane >> 2)) * K_DIM + ((lane & 3) << 3);

    const unsigned short* ard = As + (wm * 64 + ln) * SA + q * 8;
    const int swb = (ln >> 1) & 3;
    const unsigned short* brd = Bs + (wn * 64 + ln) * BK + ((q ^ swb) << 3);

    {
        #pragma unroll
        for (int j = 0; j < 2; ++j)
            __builtin_amdgcn_global_load_lds(
                (const __attribute__((address_space(1))) unsigned int*)(wtp + (size_t)j * 16 * K_DIM),
                (__attribute__((address_space(3))) unsigned int*)(Bs + (wid * 2 + j) * 512),
                16, 0, 0);
        floatx4 f0 = *(const floatx4*)(xptr);
        floatx4 f1 = *(const floatx4*)(xptr + 4);
        floatx4 f2 = *(const floatx4*)(xptr + 8);
        floatx4 f3 = *(const floatx4*)(xptr + 12);
        *(short8*)aw       = cvt8(f0, f1);
        *(short8*)(aw + 8) = cvt8(f2, f3);
    }
    __syncthreads();

    int cur = 0;
    for (int k0 = 0; k0 < K_DIM; k0 += BK) {
        const int knext = (k0 + BK) & (K_DIM - 1);
        const int nxt = cur ^ 1;

        floatx4 g0 = *(const floatx4*)(xptr + knext);
        floatx4 g1 = *(const floatx4*)(xptr + knext + 4);
        floatx4 g2 = *(const floatx4*)(xptr + knext + 8);
        floatx4 g3 = *(const floatx4*)(xptr + knext + 12);

        #pragma unroll
        for (int j = 0; j < 2; ++j)
            __builtin_amdgcn_global_load_lds(
                (const __attribute__((address_space(1))) unsigned int*)(wtp + (size_t)j * 16 * K_DIM + knext),
                (__attribute__((address_space(3))) unsigned int*)(Bs + nxt * (BN * BK) + (wid * 2 + j) * 512),
                16, 0, 0);

        short8 af[4], bfv[4];
        #pragma unroll
        for (int im = 0; im < 4; ++im)
            af[im] = *(const short8*)(ard + cur * (BM * SA) + im * 16 * SA);
        #pragma unroll
        for (int in = 0; in < 4; ++in)
            bfv[in] = *(const short8*)(brd + cur * (BN * BK) + in * 16 * BK);
        #pragma unroll
        for (int im = 0; im < 4; ++im)
            #pragma unroll
            for (int in = 0; in < 4; ++in)
                acc[im][in] = __builtin_amdgcn_mfma_f32_16x16x32_bf16(
                    af[im], bfv[in], acc[im][in], 0, 0, 0);

        *(short8*)(aw + nxt * (BM * SA))     = cvt8(g0, g1);
        *(short8*)(aw + nxt * (BM * SA) + 8) = cvt8(g2, g3);

        __syncthreads();
        cur = nxt;
    }

    epilogue(acc, m0, n0, wm, wn, q, ln, bias, mulw, out);
}

extern "C" void kernel_launch(void* const* d_in, const int* in_sizes, int n_in,
                              void* d_out, int out_size, void* d_ws, size_t ws_size,
                              hipStream_t stream) {
    const float* x  = (const float*)d_in[0];
    const float* W  = (const float*)d_in[1];
    const float* b  = (const float*)d_in[2];
    const float* mw = (const float*)d_in[3];
    float* out = (float*)d_out;
    unsigned short* Wt = (unsigned short*)d_ws;  // 2 MB

    prep_w_kernel<<<1024, 256, 0, stream>>>(W, Wt);

    const int M = in_sizes[0] / K_DIM;            // 65536
    const int grid = (M / BM) * (N_DIM / BN);     // 4096

    const size_t WT_BYTES = (size_t)N_DIM * K_DIM * sizeof(unsigned short);
    const size_t XB_BYTES = (size_t)M * K_DIM * sizeof(unsigned short);  // 128 MB

    if (ws_size >= WT_BYTES + XB_BYTES) {
        unsigned short* xb = (unsigned short*)((char*)d_ws + WT_BYTES);
        const long long nelem = (long long)M * K_DIM;
        prep_x_kernel<<<4096, 256, 0, stream>>>(x, xb, nelem);
        fused_kernel<<<grid, 256, 0, stream>>>(xb, Wt, b, mw, out);
    } else {
        fused_kernel_fb<<<grid, 256, 0, stream>>>(x, Wt, b, mw, out);
    }
}